// Round 9
// baseline (132.180 us; speedup 1.0000x reference)
//
#include <hip/hip_runtime.h>
#include <cmath>

#define SRATE 16000
#define WIN   400
#define HOP   160
#define NFFT  512
#define NBIN  257          // NFFT/2+1
#define NMELS 40
#define NMFCC 13
#define BB    64
#define LL    160000
#define NF    998          // (L-WIN)/HOP + 1

#define PI_D 3.14159265358979323846

// workspace layout (floats)
#define WS_WINDOW 0                    // 400
#define WS_W1     400                  // 64 x float2 = 128   (W_256^l)
#define WS_STW    528                  // 6 stages x 64 x float2 = 768
#define WS_UNTC   1296                 // 64 x float4 = 256 (permuted untangle cos)
#define WS_UNTS   1552                 // 64 x float4 = 256 (permuted untangle -sin)
#define WS_SM     1808                 // 64 (filter support start bin)
#define WS_FBW    1872                 // 9 jc x 64 lanes x 4 = 2304 (mel weights)
#define WS_MTT    4176                 // 39 x 40 = 1560 (fused DCT+delta, TRANSPOSED [i][n])
#define WS_TOTAL  (WS_MTT + 1560)      // 5736 floats

using v4f = __attribute__((ext_vector_type(4))) float;

__device__ __forceinline__ int brev6(int v) { return (int)(__brev((unsigned)v) >> 26); }
__device__ __forceinline__ v4f splat4(float s) { v4f r; r.x=s; r.y=s; r.z=s; r.w=s; return r; }

template<int CTRL>
__device__ __forceinline__ float dppf(float x) {
    return __int_as_float(__builtin_amdgcn_mov_dpp(__float_as_int(x), CTRL, 0xF, 0xF, true));
}
template<int CTRL>
__device__ __forceinline__ v4f dpp4(v4f v) {
    v4f r;
    r.x = dppf<CTRL>(v.x); r.y = dppf<CTRL>(v.y);
    r.z = dppf<CTRL>(v.z); r.w = dppf<CTRL>(v.w);
    return r;
}
__device__ __forceinline__ v4f sfx4(v4f v, int m) {
    v4f r;
    r.x = __shfl_xor(v.x, m, 64); r.y = __shfl_xor(v.y, m, 64);
    r.z = __shfl_xor(v.z, m, 64); r.w = __shfl_xor(v.w, m, 64);
    return r;
}
__device__ __forceinline__ v4f sfl4(v4f v, int src) {
    v4f r;
    r.x = __shfl(v.x, src, 64); r.y = __shfl(v.y, src, 64);
    r.z = __shfl(v.z, src, 64); r.w = __shfl(v.w, src, 64);
    return r;
}

// DPP controls: quad_perm xor1 = 0xB1; xor2 = 0x4E; row_ror:8 = 0x128 (xor8).
#define DPP_XOR1 0xB1
#define DPP_XOR2 0x4E
#define DPP_XOR8 0x128

// ---------------------------------------------------------------------------
// Init kernel (64 blocks): recompute constant tables every launch.
// ---------------------------------------------------------------------------
__global__ void init_tables(float* __restrict__ ws) {
    __shared__ double bins[NMELS + 2];
    const int tid = threadIdx.x;
    const int gid = blockIdx.x * 256 + tid;
    const int gstr = gridDim.x * 256;

    if (tid < NMELS + 2) {
        double high_mel = 2595.0 * log10(1.0 + ((double)SRATE / 2.0) / 700.0);
        double step = high_mel / (double)(NMELS + 1);
        double mel = (tid == NMELS + 1) ? high_mel : (double)tid * step;
        double hz = 700.0 * (pow(10.0, mel / 2595.0) - 1.0);
        bins[tid] = floor((double)(NFFT + 1) * hz / (double)SRATE);
    }
    __syncthreads();

    for (int i = gid; i < WIN; i += gstr)
        ws[WS_WINDOW + i] = (float)(0.54 - 0.46 * cos(2.0 * PI_D * (double)i / (double)WIN));

    if (gid < 64) {
        double ang = -2.0 * PI_D * (double)gid / 256.0;
        ws[WS_W1 + 2 * gid]     = (float)cos(ang);
        ws[WS_W1 + 2 * gid + 1] = (float)sin(ang);
    }

    for (int i = gid; i < 6 * 64; i += gstr) {
        int st = i >> 6, lane = i & 63;
        int h = 32 >> st;
        double cr = 1.0, ci = 0.0;
        if (lane & h) {
            double ang = -PI_D * (double)(lane & (h - 1)) / (double)h;
            cr = cos(ang); ci = sin(ang);
        }
        ws[WS_STW + st * 128 + 2 * lane]     = (float)cr;
        ws[WS_STW + st * 128 + 2 * lane + 1] = (float)ci;
    }

    for (int i = gid; i < 256; i += gstr) {
        int lane = i >> 2, k1 = i & 3;
        int m = k1 + 4 * brev6(lane);
        double ang = 2.0 * PI_D * (double)m / 512.0;
        ws[WS_UNTC + 4 * lane + k1] = (float)cos(ang);
        ws[WS_UNTS + 4 * lane + k1] = (float)(-sin(ang));
    }

    for (int i = gid; i < 64; i += gstr)
        ws[WS_SM + i] = (i < NMELS) ? (float)bins[i] : 0.0f;

    for (int i = gid; i < 9 * 256; i += gstr) {
        int jc = i >> 8, r = (i >> 2) & 63, d = i & 3;
        int j = jc * 4 + d;
        double v = 0.0;
        if (r < NMELS) {
            double flo = bins[r], fc = bins[r + 1], fhi = bins[r + 2];
            int k = (int)flo + j;
            if (k < (int)fc)        v = ((double)k - flo) / (fc - flo);
            else if (k < (int)fhi)  v = (fhi - (double)k) / (fhi - fc);
        }
        ws[WS_FBW + i] = (float)v;
    }

    for (int t = gid; t < 39 * 40; t += gstr) {
        int i = t / 40, n = t % 40;
        auto dctf = [&](int c) -> double {
            if (c < 0 || c > 39) return 0.0;
            double sc = (c == 0) ? sqrt(1.0 / 40.0) : sqrt(2.0 / 40.0);
            return sc * cos(PI_D * (double)c * (2.0 * n + 1.0) / 80.0);
        };
        auto d1f = [&](int c) -> double {
            if (c < 1 || c > 38) return 0.0;
            return 0.5 * (dctf(c + 1) - dctf(c - 1));
        };
        double v;
        if (i < 13)       v = dctf(i);
        else if (i < 26)  v = d1f(i - 13);
        else { int c = i - 26; v = (c >= 1 && c <= 38) ? 0.5 * (d1f(c + 1) - d1f(c - 1)) : 0.0; }
        ws[WS_MTT + t] = (float)v;
    }
}

// ---------------------------------------------------------------------------
// Main kernel: one WAVE per FOUR frames (v4f packed, v_pk_fma_f32 x2 per op),
// DPP shuffles for xor 1/2/8, DS shuffles for xor 4/16/32.
// ---------------------------------------------------------------------------
#define NTHREADS 256

__global__ __launch_bounds__(NTHREADS, 4) void mfcc_kernel(
    const float* __restrict__ x, const float* __restrict__ ws,
    float* __restrict__ out) {

    __shared__ __align__(16) float magI[4][1056];  // mag interleaved: [4m+frame], bins 0..263
    __shared__ __align__(16) float lmI[4][176];    // log-mel interleaved: [4n+frame]

    const int tid = threadIdx.x;
    const int w = tid >> 6;
    const int l = tid & 63;
    const int gw = blockIdx.x * 4 + w;
    const int fid0 = 4 * gw;

    const float* xp[4];
    int st[4];
    #pragma unroll
    for (int j = 0; j < 4; j++) {
        int fid = fid0 + j;
        int bb = fid / NF;
        int ff = fid - bb * NF;
        xp[j] = x + (size_t)bb * LL;
        st[j] = ff * HOP;
    }

    // ---- prefetch shared tables ----
    const float2 w1   = *(const float2*)(ws + WS_W1 + 2 * l);
    const float2 tws0 = *(const float2*)(ws + WS_STW + 0 * 128 + 2 * l);
    const float2 tws1 = *(const float2*)(ws + WS_STW + 1 * 128 + 2 * l);
    const float2 tws2 = *(const float2*)(ws + WS_STW + 2 * 128 + 2 * l);
    const float2 tws3 = *(const float2*)(ws + WS_STW + 3 * 128 + 2 * l);
    const float2 tws4 = *(const float2*)(ws + WS_STW + 4 * 128 + 2 * l);
    const int sm4 = 4 * (int)ws[WS_SM + l];

    // ---- pack 4 frames: lane l slot a holds z[l + 64a], component j = frame ----
    v4f z0r, z0i, z1r, z1i, z2r, z2i, z3r, z3i;
#define PACK(A, ZR, ZI)                                               \
    {                                                                 \
        v4f r = splat4(0.f), im = splat4(0.f);                        \
        int n2 = 2 * l + 128 * (A);                                   \
        if (n2 < WIN) {                                               \
            float2 wv = *(const float2*)(ws + WS_WINDOW + n2);        \
            _Pragma("unroll")                                         \
            for (int j = 0; j < 4; j++) {                             \
                int g = st[j] + n2;                                   \
                float2 xv = *(const float2*)(xp[j] + g);              \
                float xm = (g > 0) ? xp[j][g - 1] : 0.0f;             \
                r[j]  = (xv.x - 0.97f * xm)   * wv.x;                 \
                im[j] = (xv.y - 0.97f * xv.x) * wv.y;                 \
            }                                                         \
        }                                                             \
        ZR = r; ZI = im;                                              \
    }
    PACK(0, z0r, z0i)
    PACK(1, z1r, z1i)
    PACK(2, z2r, z2i)
    PACK(3, z3r, z3i)
#undef PACK

    // ---- in-register radix-4 over n1 (W4^1 = -i), packed ----
    {
        v4f t0r = z0r + z2r, t0i = z0i + z2i;
        v4f t1r = z0r - z2r, t1i = z0i - z2i;
        v4f t2r = z1r + z3r, t2i = z1i + z3i;
        v4f t3r = z1r - z3r, t3i = z1i - z3i;
        z0r = t0r + t2r;  z0i = t0i + t2i;
        z1r = t1r + t3i;  z1i = t1i - t3r;
        z2r = t0r - t2r;  z2i = t0i - t2i;
        z3r = t1r - t3i;  z3i = t1i + t3r;
    }

    // ---- twiddle by W_256^{l*k1}, packed ----
#define CMUL(ZR, ZI, WR, WI)                                          \
    {                                                                 \
        v4f wr = splat4(WR), wi = splat4(WI);                         \
        v4f tr = ZR * wr - ZI * wi;                                   \
        ZI = ZR * wi + ZI * wr;                                       \
        ZR = tr;                                                      \
    }
    {
        float w2r = w1.x * w1.x - w1.y * w1.y, w2i = 2.0f * w1.x * w1.y;
        float w3r = w2r * w1.x - w2i * w1.y,   w3i = w2r * w1.y + w2i * w1.x;
        CMUL(z1r, z1i, w1.x, w1.y)
        CMUL(z2r, z2i, w2r,  w2i)
        CMUL(z3r, z3i, w3r,  w3i)
    }
#undef CMUL

    // ---- 6 cross-lane DIF stages (xor 32/16/4 via DS, xor 8/2/1 via DPP) ----
#define BFLY_CORE(ZR, ZI, PR, PI, TWR, TWI, SG, LAST)                 \
    {                                                                 \
        v4f ar = __builtin_elementwise_fma(SG, ZR, PR);               \
        v4f ai = __builtin_elementwise_fma(SG, ZI, PI);               \
        if (LAST) { ZR = ar; ZI = ai; }                               \
        else { ZR = ar * TWR - ai * TWI;                              \
               ZI = ar * TWI + ai * TWR; }                            \
    }
#define STAGE_X(H, TW)                                                \
    {                                                                 \
        v4f sg = splat4((l & (H)) ? -1.0f : 1.0f);                    \
        v4f twr = splat4(TW.x), twi = splat4(TW.y);                   \
        { v4f pr = sfx4(z0r, H), pi = sfx4(z0i, H);                   \
          BFLY_CORE(z0r, z0i, pr, pi, twr, twi, sg, false) }          \
        { v4f pr = sfx4(z1r, H), pi = sfx4(z1i, H);                   \
          BFLY_CORE(z1r, z1i, pr, pi, twr, twi, sg, false) }          \
        { v4f pr = sfx4(z2r, H), pi = sfx4(z2i, H);                   \
          BFLY_CORE(z2r, z2i, pr, pi, twr, twi, sg, false) }          \
        { v4f pr = sfx4(z3r, H), pi = sfx4(z3i, H);                   \
          BFLY_CORE(z3r, z3i, pr, pi, twr, twi, sg, false) }          \
    }
#define STAGE_D(H, CTRL, TW, LAST)                                    \
    {                                                                 \
        v4f sg = splat4((l & (H)) ? -1.0f : 1.0f);                    \
        v4f twr = splat4(TW.x), twi = splat4(TW.y);                   \
        { v4f pr = dpp4<CTRL>(z0r), pi = dpp4<CTRL>(z0i);             \
          BFLY_CORE(z0r, z0i, pr, pi, twr, twi, sg, LAST) }           \
        { v4f pr = dpp4<CTRL>(z1r), pi = dpp4<CTRL>(z1i);             \
          BFLY_CORE(z1r, z1i, pr, pi, twr, twi, sg, LAST) }           \
        { v4f pr = dpp4<CTRL>(z2r), pi = dpp4<CTRL>(z2i);             \
          BFLY_CORE(z2r, z2i, pr, pi, twr, twi, sg, LAST) }           \
        { v4f pr = dpp4<CTRL>(z3r), pi = dpp4<CTRL>(z3i);             \
          BFLY_CORE(z3r, z3i, pr, pi, twr, twi, sg, LAST) }           \
    }
    STAGE_X(32, tws0)
    STAGE_X(16, tws1)
    STAGE_D(8,  DPP_XOR8, tws2, false)
    STAGE_X(4,  tws3)
    STAGE_D(2,  DPP_XOR2, tws4, false)
    STAGE_D(1,  DPP_XOR1, tws4, true)     // last: twiddle unused
#undef STAGE_X
#undef STAGE_D
#undef BFLY_CORE

    // lane l slot k1 holds Z[m], m = k1 + 4*bitrev6(l)

    // ---- rfft untangle ----
    v4f p1r = sfx4(z3r, 63), p1i = sfx4(z3i, 63);
    v4f p2r = sfx4(z2r, 63), p2i = sfx4(z2i, 63);
    v4f p3r = sfx4(z1r, 63), p3i = sfx4(z1i, 63);
    const int mrev = brev6(l);
    int q = brev6((64 - mrev) & 63);
    v4f p0r = sfl4(z0r, q), p0i = sfl4(z0i, q);

    float4 uc = *(const float4*)(ws + WS_UNTC + 4 * l);
    float4 us = *(const float4*)(ws + WS_UNTS + 4 * l);

    v4f mg0, mg1, mg2, mg3;
#define UNT(A, Bv, C, D, WR, WI, MG)                                  \
    {                                                                 \
        v4f Pr = A + C, Pi = Bv - D;                                  \
        v4f Qr = A - C, Qi = Bv + D;                                  \
        v4f wr = splat4(WR), wi = splat4(WI);                         \
        v4f Xr = splat4(0.5f) * (Pr + wi * Qr + wr * Qi);             \
        v4f Xi = splat4(0.5f) * (Pi + wi * Qi - wr * Qr);             \
        v4f s2 = __builtin_elementwise_fma(Xr, Xr, Xi * Xi);          \
        MG.x = sqrtf(s2.x); MG.y = sqrtf(s2.y);                       \
        MG.z = sqrtf(s2.z); MG.w = sqrtf(s2.w);                       \
    }
    UNT(z0r, z0i, p0r, p0i, uc.x, us.x, mg0)
    UNT(z1r, z1i, p1r, p1i, uc.y, us.y, mg1)
    UNT(z2r, z2i, p2r, p2i, uc.z, us.z, mg2)
    UNT(z3r, z3i, p3r, p3i, uc.w, us.w, mg3)
#undef UNT

    // ---- store magnitudes interleaved [4m+frame]: four b128 stores ----
    float* mw = magI[w];
    {
        *(v4f*)(mw + 16 * mrev + 0)  = mg0;
        *(v4f*)(mw + 16 * mrev + 4)  = mg1;
        *(v4f*)(mw + 16 * mrev + 8)  = mg2;
        *(v4f*)(mw + 16 * mrev + 12) = mg3;
    }
    if (l < 8) {   // zero tail bins 256..263 (overread region, weights are 0)
        *(v4f*)(mw + 1024 + 4 * l) = splat4(0.f);
    }
    __builtin_amdgcn_wave_barrier();

    // ---- mel: lane l = filter l; 36 b128 reads (4 frames each), packed FMA ----
    v4f mel = splat4(0.f);
    {
        const float* mbase = mw + sm4;
        #pragma unroll
        for (int jc = 0; jc < 9; jc++) {
            float4 fw = *(const float4*)(ws + WS_FBW + (jc * 64 + l) * 4);
            v4f ma = *(const v4f*)(mbase + 16 * jc + 0);
            v4f mb = *(const v4f*)(mbase + 16 * jc + 4);
            v4f mc = *(const v4f*)(mbase + 16 * jc + 8);
            v4f md = *(const v4f*)(mbase + 16 * jc + 12);
            mel = __builtin_elementwise_fma(splat4(fw.x), ma, mel);
            mel = __builtin_elementwise_fma(splat4(fw.y), mb, mel);
            mel = __builtin_elementwise_fma(splat4(fw.z), mc, mel);
            mel = __builtin_elementwise_fma(splat4(fw.w), md, mel);
        }
    }

    // ---- log, stage interleaved lm (one b128 write) ----
    float* lmi = lmI[w];
    if (l < NMELS) {
        v4f lg;
        lg.x = logf(mel.x + 1e-20f);
        lg.y = logf(mel.y + 1e-20f);
        lg.z = logf(mel.z + 1e-20f);
        lg.w = logf(mel.w + 1e-20f);
        *(v4f*)(lmi + 4 * l) = lg;
    }
    __builtin_amdgcn_wave_barrier();

    // ---- fused DCT+deltas matvec: 4 b128 broadcast reads per n-group ----
    v4f acc = splat4(0.f);
    int ii = (l < 39) ? l : 0;
    const float* mrow = ws + WS_MTT + ii * 40;
    #pragma unroll
    for (int g = 0; g < 10; g++) {
        float4 m4 = *(const float4*)(mrow + 4 * g);
        v4f q0 = *(const v4f*)(lmi + 16 * g + 0);
        v4f q1 = *(const v4f*)(lmi + 16 * g + 4);
        v4f q2 = *(const v4f*)(lmi + 16 * g + 8);
        v4f q3 = *(const v4f*)(lmi + 16 * g + 12);
        acc = __builtin_elementwise_fma(splat4(m4.x), q0, acc);
        acc = __builtin_elementwise_fma(splat4(m4.y), q1, acc);
        acc = __builtin_elementwise_fma(splat4(m4.z), q2, acc);
        acc = __builtin_elementwise_fma(splat4(m4.w), q3, acc);
    }
    if (l < 39) {
        #pragma unroll
        for (int j = 0; j < 4; j++)
            out[(size_t)(fid0 + j) * 39 + l] = acc[j];
    }
}

// ---------------------------------------------------------------------------
extern "C" void kernel_launch(void* const* d_in, const int* in_sizes, int n_in,
                              void* d_out, int out_size, void* d_ws, size_t ws_size,
                              hipStream_t stream) {
    const float* x = (const float*)d_in[0];
    float* ws = (float*)d_ws;
    float* out = (float*)d_out;

    init_tables<<<64, 256, 0, stream>>>(ws);
    mfcc_kernel<<<(BB * NF) / 16, NTHREADS, 0, stream>>>(x, ws, out);
}

// Round 10
// 128.796 us; speedup vs baseline: 1.0263x; 1.0263x over previous
//
#include <hip/hip_runtime.h>
#include <cmath>

#define SRATE 16000
#define WIN   400
#define HOP   160
#define NFFT  512
#define NBIN  257          // NFFT/2+1
#define NMELS 40
#define NMFCC 13
#define BB    64
#define LL    160000
#define NF    998          // (L-WIN)/HOP + 1

#define PI_D 3.14159265358979323846

// workspace layout (floats)
#define WS_WINDOW 0                    // 400
#define WS_W1     400                  // 64 x float2 = 128   (W_256^l)
#define WS_STW    528                  // 6 stages x 64 x float2 = 768
#define WS_UNTC   1296                 // 64 x float4 = 256 (permuted untangle cos)
#define WS_UNTS   1552                 // 64 x float4 = 256 (permuted untangle -sin)
#define WS_SM     1808                 // 64 (filter support start bin)
#define WS_FBW    1872                 // 9 jc x 64 lanes x 4 = 2304 (mel weights)
#define WS_MTT    4176                 // 39 x 40 = 1560 (fused DCT+delta, TRANSPOSED [i][n])
#define WS_TOTAL  (WS_MTT + 1560)      // 5736 floats

using v2f = __attribute__((ext_vector_type(2))) float;

__device__ __forceinline__ int brev6(int v) { return (int)(__brev((unsigned)v) >> 26); }
__device__ __forceinline__ v2f splat(float s) { v2f r; r.x = s; r.y = s; return r; }

template<int CTRL>
__device__ __forceinline__ float dppf(float x) {
    return __int_as_float(__builtin_amdgcn_mov_dpp(__float_as_int(x), CTRL, 0xF, 0xF, true));
}
template<int CTRL>
__device__ __forceinline__ v2f dpp2(v2f v) {
    v2f r; r.x = dppf<CTRL>(v.x); r.y = dppf<CTRL>(v.y); return r;
}
__device__ __forceinline__ v2f sfx2(v2f v, int m) {
    v2f r; r.x = __shfl_xor(v.x, m, 64); r.y = __shfl_xor(v.y, m, 64); return r;
}
__device__ __forceinline__ v2f sfl2(v2f v, int src) {
    v2f r; r.x = __shfl(v.x, src, 64); r.y = __shfl(v.y, src, 64); return r;
}

// DPP controls: quad_perm xor1 = [1,0,3,2] = 0xB1; xor2 = [2,3,0,1] = 0x4E;
// row_ror:8 = 0x128 (== xor8 within each 16-lane row).
#define DPP_XOR1 0xB1
#define DPP_XOR2 0x4E
#define DPP_XOR8 0x128

// ---------------------------------------------------------------------------
// Init kernel (64 blocks): recompute constant tables every launch.
// ---------------------------------------------------------------------------
__global__ void init_tables(float* __restrict__ ws) {
    __shared__ double bins[NMELS + 2];
    const int tid = threadIdx.x;
    const int gid = blockIdx.x * 256 + tid;
    const int gstr = gridDim.x * 256;

    if (tid < NMELS + 2) {
        double high_mel = 2595.0 * log10(1.0 + ((double)SRATE / 2.0) / 700.0);
        double step = high_mel / (double)(NMELS + 1);
        double mel = (tid == NMELS + 1) ? high_mel : (double)tid * step;
        double hz = 700.0 * (pow(10.0, mel / 2595.0) - 1.0);
        bins[tid] = floor((double)(NFFT + 1) * hz / (double)SRATE);
    }
    __syncthreads();

    for (int i = gid; i < WIN; i += gstr)
        ws[WS_WINDOW + i] = (float)(0.54 - 0.46 * cos(2.0 * PI_D * (double)i / (double)WIN));

    if (gid < 64) {
        double ang = -2.0 * PI_D * (double)gid / 256.0;
        ws[WS_W1 + 2 * gid]     = (float)cos(ang);
        ws[WS_W1 + 2 * gid + 1] = (float)sin(ang);
    }

    for (int i = gid; i < 6 * 64; i += gstr) {
        int st = i >> 6, lane = i & 63;
        int h = 32 >> st;
        double cr = 1.0, ci = 0.0;
        if (lane & h) {
            double ang = -PI_D * (double)(lane & (h - 1)) / (double)h;
            cr = cos(ang); ci = sin(ang);
        }
        ws[WS_STW + st * 128 + 2 * lane]     = (float)cr;
        ws[WS_STW + st * 128 + 2 * lane + 1] = (float)ci;
    }

    for (int i = gid; i < 256; i += gstr) {
        int lane = i >> 2, k1 = i & 3;
        int m = k1 + 4 * brev6(lane);
        double ang = 2.0 * PI_D * (double)m / 512.0;
        ws[WS_UNTC + 4 * lane + k1] = (float)cos(ang);
        ws[WS_UNTS + 4 * lane + k1] = (float)(-sin(ang));
    }

    for (int i = gid; i < 64; i += gstr)
        ws[WS_SM + i] = (i < NMELS) ? (float)bins[i] : 0.0f;

    for (int i = gid; i < 9 * 256; i += gstr) {
        int jc = i >> 8, r = (i >> 2) & 63, d = i & 3;
        int j = jc * 4 + d;
        double v = 0.0;
        if (r < NMELS) {
            double flo = bins[r], fc = bins[r + 1], fhi = bins[r + 2];
            int k = (int)flo + j;
            if (k < (int)fc)        v = ((double)k - flo) / (fc - flo);
            else if (k < (int)fhi)  v = (fhi - (double)k) / (fhi - fc);
        }
        ws[WS_FBW + i] = (float)v;
    }

    for (int t = gid; t < 39 * 40; t += gstr) {
        int i = t / 40, n = t % 40;
        auto dctf = [&](int c) -> double {
            if (c < 0 || c > 39) return 0.0;
            double sc = (c == 0) ? sqrt(1.0 / 40.0) : sqrt(2.0 / 40.0);
            return sc * cos(PI_D * (double)c * (2.0 * n + 1.0) / 80.0);
        };
        auto d1f = [&](int c) -> double {
            if (c < 1 || c > 38) return 0.0;
            return 0.5 * (dctf(c + 1) - dctf(c - 1));
        };
        double v;
        if (i < 13)       v = dctf(i);
        else if (i < 26)  v = d1f(i - 13);
        else { int c = i - 26; v = (c >= 1 && c <= 38) ? 0.5 * (d1f(c + 1) - d1f(c - 1)) : 0.0; }
        ws[WS_MTT + t] = (float)v;
    }
}

// ---------------------------------------------------------------------------
// Main kernel: one WAVE per TWO adjacent frames, v2f packed math (v_pk_fma),
// DPP shuffles for xor 1/2/8, DS shuffles only for xor 4/16/32.
// __launch_bounds__(256,8): 8 blocks/CU (VGPR<=64, LDS 10.2KB x 8 = 82KB).
// ---------------------------------------------------------------------------
#define NTHREADS 256

__global__ __launch_bounds__(NTHREADS, 8) void mfcc_kernel(
    const float* __restrict__ x, const float* __restrict__ ws,
    float* __restrict__ out) {

    __shared__ __align__(16) float magI[4][528];   // interleaved mag: [2m+frame]
    __shared__ __align__(16) float lmI[4][88];     // interleaved log-mel

    const int tid = threadIdx.x;
    const int w = tid >> 6;
    const int l = tid & 63;
    const int gw = blockIdx.x * 4 + w;
    const int fid0 = 2 * gw;
    const int fid1 = fid0 + 1;
    const int b0 = fid0 / NF, f0 = fid0 - b0 * NF;
    const int b1 = fid1 / NF, f1 = fid1 - b1 * NF;
    const float* xp0 = x + (size_t)b0 * LL;
    const float* xp1 = x + (size_t)b1 * LL;
    const int st0 = f0 * HOP, st1 = f1 * HOP;

    // ---- prefetch shared tables ----
    const float2 w1   = *(const float2*)(ws + WS_W1 + 2 * l);
    const float2 tws0 = *(const float2*)(ws + WS_STW + 0 * 128 + 2 * l);
    const float2 tws1 = *(const float2*)(ws + WS_STW + 1 * 128 + 2 * l);
    const float2 tws2 = *(const float2*)(ws + WS_STW + 2 * 128 + 2 * l);
    const float2 tws3 = *(const float2*)(ws + WS_STW + 3 * 128 + 2 * l);
    const float2 tws4 = *(const float2*)(ws + WS_STW + 4 * 128 + 2 * l);
    const int sm2 = 2 * (int)ws[WS_SM + l];

    // ---- pack both frames: lane l slot a holds z[l + 64a] ----
    v2f z0r, z0i, z1r, z1i, z2r, z2i, z3r, z3i;
#define PACK(A, ZR, ZI)                                               \
    {                                                                 \
        v2f r = splat(0.f), im = splat(0.f);                          \
        int n2 = 2 * l + 128 * (A);                                   \
        if (n2 < WIN) {                                               \
            float2 wv = *(const float2*)(ws + WS_WINDOW + n2);        \
            int g0 = st0 + n2;                                        \
            float2 xv0 = *(const float2*)(xp0 + g0);                  \
            float xm0 = (g0 > 0) ? xp0[g0 - 1] : 0.0f;                \
            int g1 = st1 + n2;                                        \
            float2 xv1 = *(const float2*)(xp1 + g1);                  \
            float xm1 = (g1 > 0) ? xp1[g1 - 1] : 0.0f;                \
            r.x  = (xv0.x - 0.97f * xm0)   * wv.x;                    \
            im.x = (xv0.y - 0.97f * xv0.x) * wv.y;                    \
            r.y  = (xv1.x - 0.97f * xm1)   * wv.x;                    \
            im.y = (xv1.y - 0.97f * xv1.x) * wv.y;                    \
        }                                                             \
        ZR = r; ZI = im;                                              \
    }
    PACK(0, z0r, z0i)
    PACK(1, z1r, z1i)
    PACK(2, z2r, z2i)
    PACK(3, z3r, z3i)
#undef PACK

    // ---- in-register radix-4 over n1 (W4^1 = -i), packed ----
    {
        v2f t0r = z0r + z2r, t0i = z0i + z2i;
        v2f t1r = z0r - z2r, t1i = z0i - z2i;
        v2f t2r = z1r + z3r, t2i = z1i + z3i;
        v2f t3r = z1r - z3r, t3i = z1i - z3i;
        z0r = t0r + t2r;  z0i = t0i + t2i;
        z1r = t1r + t3i;  z1i = t1i - t3r;
        z2r = t0r - t2r;  z2i = t0i - t2i;
        z3r = t1r - t3i;  z3i = t1i + t3r;
    }

    // ---- twiddle by W_256^{l*k1}, packed ----
#define CMUL(ZR, ZI, WR, WI)                                          \
    {                                                                 \
        v2f wr = splat(WR), wi = splat(WI);                           \
        v2f tr = ZR * wr - ZI * wi;                                   \
        ZI = ZR * wi + ZI * wr;                                       \
        ZR = tr;                                                      \
    }
    {
        float w2r = w1.x * w1.x - w1.y * w1.y, w2i = 2.0f * w1.x * w1.y;
        float w3r = w2r * w1.x - w2i * w1.y,   w3i = w2r * w1.y + w2i * w1.x;
        CMUL(z1r, z1i, w1.x, w1.y)
        CMUL(z2r, z2i, w2r,  w2i)
        CMUL(z3r, z3i, w3r,  w3i)
    }
#undef CMUL

    // ---- 6 cross-lane DIF stages (xor 32/16/4 via DS, xor 8/2/1 via DPP) ----
#define BFLY_CORE(ZR, ZI, PR, PI, TWR, TWI, SG, LAST)                 \
    {                                                                 \
        v2f ar = __builtin_elementwise_fma(SG, ZR, PR);               \
        v2f ai = __builtin_elementwise_fma(SG, ZI, PI);               \
        if (LAST) { ZR = ar; ZI = ai; }                               \
        else { ZR = ar * TWR - ai * TWI;                              \
               ZI = ar * TWI + ai * TWR; }                            \
    }
#define STAGE_X(H, TW)                                                \
    {                                                                 \
        v2f sg = splat((l & (H)) ? -1.0f : 1.0f);                     \
        v2f twr = splat(TW.x), twi = splat(TW.y);                     \
        { v2f pr = sfx2(z0r, H), pi = sfx2(z0i, H);                   \
          BFLY_CORE(z0r, z0i, pr, pi, twr, twi, sg, false) }          \
        { v2f pr = sfx2(z1r, H), pi = sfx2(z1i, H);                   \
          BFLY_CORE(z1r, z1i, pr, pi, twr, twi, sg, false) }          \
        { v2f pr = sfx2(z2r, H), pi = sfx2(z2i, H);                   \
          BFLY_CORE(z2r, z2i, pr, pi, twr, twi, sg, false) }          \
        { v2f pr = sfx2(z3r, H), pi = sfx2(z3i, H);                   \
          BFLY_CORE(z3r, z3i, pr, pi, twr, twi, sg, false) }          \
    }
#define STAGE_D(H, CTRL, TW, LAST)                                    \
    {                                                                 \
        v2f sg = splat((l & (H)) ? -1.0f : 1.0f);                     \
        v2f twr = splat(TW.x), twi = splat(TW.y);                     \
        { v2f pr = dpp2<CTRL>(z0r), pi = dpp2<CTRL>(z0i);             \
          BFLY_CORE(z0r, z0i, pr, pi, twr, twi, sg, LAST) }           \
        { v2f pr = dpp2<CTRL>(z1r), pi = dpp2<CTRL>(z1i);             \
          BFLY_CORE(z1r, z1i, pr, pi, twr, twi, sg, LAST) }           \
        { v2f pr = dpp2<CTRL>(z2r), pi = dpp2<CTRL>(z2i);             \
          BFLY_CORE(z2r, z2i, pr, pi, twr, twi, sg, LAST) }           \
        { v2f pr = dpp2<CTRL>(z3r), pi = dpp2<CTRL>(z3i);             \
          BFLY_CORE(z3r, z3i, pr, pi, twr, twi, sg, LAST) }           \
    }
    STAGE_X(32, tws0)
    STAGE_X(16, tws1)
    STAGE_D(8,  DPP_XOR8, tws2, false)
    STAGE_X(4,  tws3)
    STAGE_D(2,  DPP_XOR2, tws4, false)
    STAGE_D(1,  DPP_XOR1, tws4, true)     // last: twiddle unused
#undef STAGE_X
#undef STAGE_D
#undef BFLY_CORE

    // lane l slot k1 holds Z[m], m = k1 + 4*bitrev6(l)

    // ---- rfft untangle ----
    v2f p1r = sfx2(z3r, 63), p1i = sfx2(z3i, 63);
    v2f p2r = sfx2(z2r, 63), p2i = sfx2(z2i, 63);
    v2f p3r = sfx2(z1r, 63), p3i = sfx2(z1i, 63);
    const int mrev = brev6(l);
    int q = brev6((64 - mrev) & 63);
    v2f p0r = sfl2(z0r, q), p0i = sfl2(z0i, q);

    float4 uc = *(const float4*)(ws + WS_UNTC + 4 * l);
    float4 us = *(const float4*)(ws + WS_UNTS + 4 * l);

    v2f mg0, mg1, mg2, mg3;
#define UNT(A, Bv, C, D, WR, WI, MG)                                  \
    {                                                                 \
        v2f Pr = A + C, Pi = Bv - D;                                  \
        v2f Qr = A - C, Qi = Bv + D;                                  \
        v2f wr = splat(WR), wi = splat(WI);                           \
        v2f Xr = splat(0.5f) * (Pr + wi * Qr + wr * Qi);              \
        v2f Xi = splat(0.5f) * (Pi + wi * Qi - wr * Qr);              \
        v2f s2 = __builtin_elementwise_fma(Xr, Xr, Xi * Xi);          \
        MG.x = sqrtf(s2.x); MG.y = sqrtf(s2.y);                       \
    }
    UNT(z0r, z0i, p0r, p0i, uc.x, us.x, mg0)
    UNT(z1r, z1i, p1r, p1i, uc.y, us.y, mg1)
    UNT(z2r, z2i, p2r, p2i, uc.z, us.z, mg2)
    UNT(z3r, z3i, p3r, p3i, uc.w, us.w, mg3)
#undef UNT

    // ---- store magnitudes interleaved: two b128 stores ----
    float* mw = magI[w];
    {
        float4 s0 = make_float4(mg0.x, mg0.y, mg1.x, mg1.y);
        float4 s1 = make_float4(mg2.x, mg2.y, mg3.x, mg3.y);
        *(float4*)(mw + 8 * mrev)     = s0;
        *(float4*)(mw + 8 * mrev + 4) = s1;
    }
    if (l < 4) {   // zero tail bins 256..263 (overread region, weights are 0)
        *(float4*)(mw + 512 + 4 * l) = make_float4(0.f, 0.f, 0.f, 0.f);
    }
    __builtin_amdgcn_wave_barrier();

    // ---- mel: lane l = filter l; 36 b64 reads, packed FMA ----
    v2f mel = splat(0.f);
    {
        const float* mbase = mw + sm2;
        #pragma unroll
        for (int jc = 0; jc < 9; jc++) {
            float4 fw = *(const float4*)(ws + WS_FBW + (jc * 64 + l) * 4);
            v2f ma = *(const v2f*)(mbase + 8 * jc + 0);
            v2f mb = *(const v2f*)(mbase + 8 * jc + 2);
            v2f mc = *(const v2f*)(mbase + 8 * jc + 4);
            v2f md = *(const v2f*)(mbase + 8 * jc + 6);
            mel = __builtin_elementwise_fma(splat(fw.x), ma, mel);
            mel = __builtin_elementwise_fma(splat(fw.y), mb, mel);
            mel = __builtin_elementwise_fma(splat(fw.z), mc, mel);
            mel = __builtin_elementwise_fma(splat(fw.w), md, mel);
        }
    }

    // ---- log, stage interleaved lm (one b64 write) ----
    float* lmi = lmI[w];
    if (l < NMELS) {
        v2f lg;
        lg.x = logf(mel.x + 1e-20f);
        lg.y = logf(mel.y + 1e-20f);
        *(v2f*)(lmi + 2 * l) = lg;
    }
    __builtin_amdgcn_wave_barrier();

    // ---- fused DCT+deltas matvec: b128 broadcast reads give packed pairs ----
    v2f acc = splat(0.f);
    int ii = (l < 39) ? l : 0;
    const float* mrow = ws + WS_MTT + ii * 40;
    #pragma unroll
    for (int g = 0; g < 10; g++) {
        float4 m4 = *(const float4*)(mrow + 4 * g);
        float4 q0 = *(const float4*)(lmi + 8 * g);
        float4 q1 = *(const float4*)(lmi + 8 * g + 4);
        v2f p0; p0.x = q0.x; p0.y = q0.y;
        v2f p1; p1.x = q0.z; p1.y = q0.w;
        v2f p2; p2.x = q1.x; p2.y = q1.y;
        v2f p3; p3.x = q1.z; p3.y = q1.w;
        acc = __builtin_elementwise_fma(splat(m4.x), p0, acc);
        acc = __builtin_elementwise_fma(splat(m4.y), p1, acc);
        acc = __builtin_elementwise_fma(splat(m4.z), p2, acc);
        acc = __builtin_elementwise_fma(splat(m4.w), p3, acc);
    }
    if (l < 39) {
        out[(size_t)fid0 * 39 + l] = acc.x;
        out[(size_t)fid1 * 39 + l] = acc.y;
    }
}

// ---------------------------------------------------------------------------
extern "C" void kernel_launch(void* const* d_in, const int* in_sizes, int n_in,
                              void* d_out, int out_size, void* d_ws, size_t ws_size,
                              hipStream_t stream) {
    const float* x = (const float*)d_in[0];
    float* ws = (float*)d_ws;
    float* out = (float*)d_out;

    init_tables<<<64, 256, 0, stream>>>(ws);
    mfcc_kernel<<<(BB * NF) / 8, NTHREADS, 0, stream>>>(x, ws, out);
}

// Round 11
// 127.338 us; speedup vs baseline: 1.0380x; 1.0115x over previous
//
#include <hip/hip_runtime.h>
#include <cmath>

#define SRATE 16000
#define WIN   400
#define HOP   160
#define NFFT  512
#define NBIN  257          // NFFT/2+1
#define NMELS 40
#define NMFCC 13
#define BB    64
#define LL    160000
#define NF    998          // (L-WIN)/HOP + 1

#define PI_D 3.14159265358979323846

// workspace layout (floats)
#define WS_WINDOW 0                    // 400 (pre-scaled by 0.5: folds rfft-untangle factor)
#define WS_W1     400                  // 64 x float2 = 128   (W_256^l)
#define WS_STW    528                  // 6 stages x 64 x float2 = 768
#define WS_UNTC   1296                 // 64 x float4 = 256 (permuted untangle cos)
#define WS_UNTS   1552                 // 64 x float4 = 256 (permuted untangle -sin)
#define WS_SM     1808                 // 64 (filter support start bin)
#define WS_FBW    1872                 // 9 jc x 64 lanes x 4 = 2304 (mel weights)
#define WS_MTT    4176                 // 39 x 40 = 1560 (fused DCT+delta, TRANSPOSED [i][n])
#define WS_TOTAL  (WS_MTT + 1560)      // 5736 floats

using v2f = __attribute__((ext_vector_type(2))) float;

__device__ __forceinline__ int brev6(int v) { return (int)(__brev((unsigned)v) >> 26); }
__device__ __forceinline__ v2f splat(float s) { v2f r; r.x = s; r.y = s; return r; }

template<int CTRL>
__device__ __forceinline__ float dppf(float x) {
    return __int_as_float(__builtin_amdgcn_mov_dpp(__float_as_int(x), CTRL, 0xF, 0xF, true));
}
template<int CTRL>
__device__ __forceinline__ v2f dpp2(v2f v) {
    v2f r; r.x = dppf<CTRL>(v.x); r.y = dppf<CTRL>(v.y); return r;
}
__device__ __forceinline__ v2f sfx2(v2f v, int m) {
    v2f r; r.x = __shfl_xor(v.x, m, 64); r.y = __shfl_xor(v.y, m, 64); return r;
}
__device__ __forceinline__ v2f sfl2(v2f v, int src) {
    v2f r; r.x = __shfl(v.x, src, 64); r.y = __shfl(v.y, src, 64); return r;
}

// DPP controls: quad_perm xor1 = [1,0,3,2] = 0xB1; xor2 = [2,3,0,1] = 0x4E;
// row_ror:8 = 0x128 (== xor8 within each 16-lane row).
#define DPP_XOR1 0xB1
#define DPP_XOR2 0x4E
#define DPP_XOR8 0x128

// ---------------------------------------------------------------------------
// Init kernel (64 blocks): recompute constant tables every launch.
// ---------------------------------------------------------------------------
__global__ void init_tables(float* __restrict__ ws) {
    __shared__ double bins[NMELS + 2];
    const int tid = threadIdx.x;
    const int gid = blockIdx.x * 256 + tid;
    const int gstr = gridDim.x * 256;

    if (tid < NMELS + 2) {
        double high_mel = 2595.0 * log10(1.0 + ((double)SRATE / 2.0) / 700.0);
        double step = high_mel / (double)(NMELS + 1);
        double mel = (tid == NMELS + 1) ? high_mel : (double)tid * step;
        double hz = 700.0 * (pow(10.0, mel / 2595.0) - 1.0);
        bins[tid] = floor((double)(NFFT + 1) * hz / (double)SRATE);
    }
    __syncthreads();

    // Hamming window pre-scaled by 0.5 (the rfft-untangle 0.5 factor, folded:
    // the FFT and untangle are linear, so scaling z scales X uniformly).
    for (int i = gid; i < WIN; i += gstr)
        ws[WS_WINDOW + i] = (float)(0.5 * (0.54 - 0.46 * cos(2.0 * PI_D * (double)i / (double)WIN)));

    if (gid < 64) {
        double ang = -2.0 * PI_D * (double)gid / 256.0;
        ws[WS_W1 + 2 * gid]     = (float)cos(ang);
        ws[WS_W1 + 2 * gid + 1] = (float)sin(ang);
    }

    for (int i = gid; i < 6 * 64; i += gstr) {
        int st = i >> 6, lane = i & 63;
        int h = 32 >> st;
        double cr = 1.0, ci = 0.0;
        if (lane & h) {
            double ang = -PI_D * (double)(lane & (h - 1)) / (double)h;
            cr = cos(ang); ci = sin(ang);
        }
        ws[WS_STW + st * 128 + 2 * lane]     = (float)cr;
        ws[WS_STW + st * 128 + 2 * lane + 1] = (float)ci;
    }

    for (int i = gid; i < 256; i += gstr) {
        int lane = i >> 2, k1 = i & 3;
        int m = k1 + 4 * brev6(lane);
        double ang = 2.0 * PI_D * (double)m / 512.0;
        ws[WS_UNTC + 4 * lane + k1] = (float)cos(ang);
        ws[WS_UNTS + 4 * lane + k1] = (float)(-sin(ang));
    }

    for (int i = gid; i < 64; i += gstr)
        ws[WS_SM + i] = (i < NMELS) ? (float)bins[i] : 0.0f;

    for (int i = gid; i < 9 * 256; i += gstr) {
        int jc = i >> 8, r = (i >> 2) & 63, d = i & 3;
        int j = jc * 4 + d;
        double v = 0.0;
        if (r < NMELS) {
            double flo = bins[r], fc = bins[r + 1], fhi = bins[r + 2];
            int k = (int)flo + j;
            if (k < (int)fc)        v = ((double)k - flo) / (fc - flo);
            else if (k < (int)fhi)  v = (fhi - (double)k) / (fhi - fc);
        }
        ws[WS_FBW + i] = (float)v;
    }

    for (int t = gid; t < 39 * 40; t += gstr) {
        int i = t / 40, n = t % 40;
        auto dctf = [&](int c) -> double {
            if (c < 0 || c > 39) return 0.0;
            double sc = (c == 0) ? sqrt(1.0 / 40.0) : sqrt(2.0 / 40.0);
            return sc * cos(PI_D * (double)c * (2.0 * n + 1.0) / 80.0);
        };
        auto d1f = [&](int c) -> double {
            if (c < 1 || c > 38) return 0.0;
            return 0.5 * (dctf(c + 1) - dctf(c - 1));
        };
        double v;
        if (i < 13)       v = dctf(i);
        else if (i < 26)  v = d1f(i - 13);
        else { int c = i - 26; v = (c >= 1 && c <= 38) ? 0.5 * (d1f(c + 1) - d1f(c - 1)) : 0.0; }
        ws[WS_MTT + t] = (float)v;
    }
}

// ---------------------------------------------------------------------------
// Main kernel: one WAVE per TWO adjacent frames, v2f packed math (v_pk_fma),
// DPP shuffles for xor 1/2/8, DS shuffles only for xor 4/16/32.
// __launch_bounds__(256,6): R8's measured-best codegen (66.5 us).
// ---------------------------------------------------------------------------
#define NTHREADS 256

__global__ __launch_bounds__(NTHREADS, 6) void mfcc_kernel(
    const float* __restrict__ x, const float* __restrict__ ws,
    float* __restrict__ out) {

    __shared__ __align__(16) float magI[4][528];   // interleaved mag: [2m+frame]
    __shared__ __align__(16) float lmI[4][88];     // interleaved log-mel

    const int tid = threadIdx.x;
    const int w = tid >> 6;
    const int l = tid & 63;
    const int gw = blockIdx.x * 4 + w;
    const int fid0 = 2 * gw;
    const int fid1 = fid0 + 1;
    const int b0 = fid0 / NF, f0 = fid0 - b0 * NF;
    const int b1 = fid1 / NF, f1 = fid1 - b1 * NF;
    const float* xp0 = x + (size_t)b0 * LL;
    const float* xp1 = x + (size_t)b1 * LL;
    const int st0 = f0 * HOP, st1 = f1 * HOP;

    // ---- prefetch shared tables ----
    const float2 w1   = *(const float2*)(ws + WS_W1 + 2 * l);
    const float2 tws0 = *(const float2*)(ws + WS_STW + 0 * 128 + 2 * l);
    const float2 tws1 = *(const float2*)(ws + WS_STW + 1 * 128 + 2 * l);
    const float2 tws2 = *(const float2*)(ws + WS_STW + 2 * 128 + 2 * l);
    const float2 tws3 = *(const float2*)(ws + WS_STW + 3 * 128 + 2 * l);
    const float2 tws4 = *(const float2*)(ws + WS_STW + 4 * 128 + 2 * l);
    const int sm2 = 2 * (int)ws[WS_SM + l];

    // ---- pack both frames: lane l slot a holds z[l + 64a] ----
    v2f z0r, z0i, z1r, z1i, z2r, z2i, z3r, z3i;
#define PACK(A, ZR, ZI)                                               \
    {                                                                 \
        v2f r = splat(0.f), im = splat(0.f);                          \
        int n2 = 2 * l + 128 * (A);                                   \
        if (n2 < WIN) {                                               \
            float2 wv = *(const float2*)(ws + WS_WINDOW + n2);        \
            int g0 = st0 + n2;                                        \
            float2 xv0 = *(const float2*)(xp0 + g0);                  \
            float xm0 = (g0 > 0) ? xp0[g0 - 1] : 0.0f;                \
            int g1 = st1 + n2;                                        \
            float2 xv1 = *(const float2*)(xp1 + g1);                  \
            float xm1 = (g1 > 0) ? xp1[g1 - 1] : 0.0f;                \
            r.x  = (xv0.x - 0.97f * xm0)   * wv.x;                    \
            im.x = (xv0.y - 0.97f * xv0.x) * wv.y;                    \
            r.y  = (xv1.x - 0.97f * xm1)   * wv.x;                    \
            im.y = (xv1.y - 0.97f * xv1.x) * wv.y;                    \
        }                                                             \
        ZR = r; ZI = im;                                              \
    }
    PACK(0, z0r, z0i)
    PACK(1, z1r, z1i)
    PACK(2, z2r, z2i)
    PACK(3, z3r, z3i)
#undef PACK

    // ---- in-register radix-4 over n1 (W4^1 = -i), packed ----
    {
        v2f t0r = z0r + z2r, t0i = z0i + z2i;
        v2f t1r = z0r - z2r, t1i = z0i - z2i;
        v2f t2r = z1r + z3r, t2i = z1i + z3i;
        v2f t3r = z1r - z3r, t3i = z1i - z3i;
        z0r = t0r + t2r;  z0i = t0i + t2i;
        z1r = t1r + t3i;  z1i = t1i - t3r;
        z2r = t0r - t2r;  z2i = t0i - t2i;
        z3r = t1r - t3i;  z3i = t1i + t3r;
    }

    // ---- twiddle by W_256^{l*k1}, packed ----
#define CMUL(ZR, ZI, WR, WI)                                          \
    {                                                                 \
        v2f wr = splat(WR), wi = splat(WI);                           \
        v2f tr = ZR * wr - ZI * wi;                                   \
        ZI = ZR * wi + ZI * wr;                                       \
        ZR = tr;                                                      \
    }
    {
        float w2r = w1.x * w1.x - w1.y * w1.y, w2i = 2.0f * w1.x * w1.y;
        float w3r = w2r * w1.x - w2i * w1.y,   w3i = w2r * w1.y + w2i * w1.x;
        CMUL(z1r, z1i, w1.x, w1.y)
        CMUL(z2r, z2i, w2r,  w2i)
        CMUL(z3r, z3i, w3r,  w3i)
    }
#undef CMUL

    // ---- 6 cross-lane DIF stages (xor 32/16/4 via DS, xor 8/2/1 via DPP) ----
#define BFLY_CORE(ZR, ZI, PR, PI, TWR, TWI, SG, LAST)                 \
    {                                                                 \
        v2f ar = __builtin_elementwise_fma(SG, ZR, PR);               \
        v2f ai = __builtin_elementwise_fma(SG, ZI, PI);               \
        if (LAST) { ZR = ar; ZI = ai; }                               \
        else { ZR = ar * TWR - ai * TWI;                              \
               ZI = ar * TWI + ai * TWR; }                            \
    }
#define STAGE_X(H, TW)                                                \
    {                                                                 \
        v2f sg = splat((l & (H)) ? -1.0f : 1.0f);                     \
        v2f twr = splat(TW.x), twi = splat(TW.y);                     \
        { v2f pr = sfx2(z0r, H), pi = sfx2(z0i, H);                   \
          BFLY_CORE(z0r, z0i, pr, pi, twr, twi, sg, false) }          \
        { v2f pr = sfx2(z1r, H), pi = sfx2(z1i, H);                   \
          BFLY_CORE(z1r, z1i, pr, pi, twr, twi, sg, false) }          \
        { v2f pr = sfx2(z2r, H), pi = sfx2(z2i, H);                   \
          BFLY_CORE(z2r, z2i, pr, pi, twr, twi, sg, false) }          \
        { v2f pr = sfx2(z3r, H), pi = sfx2(z3i, H);                   \
          BFLY_CORE(z3r, z3i, pr, pi, twr, twi, sg, false) }          \
    }
#define STAGE_D(H, CTRL, TW, LAST)                                    \
    {                                                                 \
        v2f sg = splat((l & (H)) ? -1.0f : 1.0f);                     \
        v2f twr = splat(TW.x), twi = splat(TW.y);                     \
        { v2f pr = dpp2<CTRL>(z0r), pi = dpp2<CTRL>(z0i);             \
          BFLY_CORE(z0r, z0i, pr, pi, twr, twi, sg, LAST) }           \
        { v2f pr = dpp2<CTRL>(z1r), pi = dpp2<CTRL>(z1i);             \
          BFLY_CORE(z1r, z1i, pr, pi, twr, twi, sg, LAST) }           \
        { v2f pr = dpp2<CTRL>(z2r), pi = dpp2<CTRL>(z2i);             \
          BFLY_CORE(z2r, z2i, pr, pi, twr, twi, sg, LAST) }           \
        { v2f pr = dpp2<CTRL>(z3r), pi = dpp2<CTRL>(z3i);             \
          BFLY_CORE(z3r, z3i, pr, pi, twr, twi, sg, LAST) }           \
    }
    STAGE_X(32, tws0)
    STAGE_X(16, tws1)
    STAGE_D(8,  DPP_XOR8, tws2, false)
    STAGE_X(4,  tws3)
    STAGE_D(2,  DPP_XOR2, tws4, false)
    STAGE_D(1,  DPP_XOR1, tws4, true)     // last: twiddle unused
#undef STAGE_X
#undef STAGE_D
#undef BFLY_CORE

    // lane l slot k1 holds Z[m], m = k1 + 4*bitrev6(l)  (all scaled by 0.5)

    // ---- rfft untangle (0.5 factor already folded into window) ----
    v2f p1r = sfx2(z3r, 63), p1i = sfx2(z3i, 63);
    v2f p2r = sfx2(z2r, 63), p2i = sfx2(z2i, 63);
    v2f p3r = sfx2(z1r, 63), p3i = sfx2(z1i, 63);
    const int mrev = brev6(l);
    int q = brev6((64 - mrev) & 63);
    v2f p0r = sfl2(z0r, q), p0i = sfl2(z0i, q);

    float4 uc = *(const float4*)(ws + WS_UNTC + 4 * l);
    float4 us = *(const float4*)(ws + WS_UNTS + 4 * l);

    v2f mg0, mg1, mg2, mg3;
#define UNT(A, Bv, C, D, WR, WI, MG)                                  \
    {                                                                 \
        v2f Pr = A + C, Pi = Bv - D;                                  \
        v2f Qr = A - C, Qi = Bv + D;                                  \
        v2f wr = splat(WR), wi = splat(WI);                           \
        v2f Xr = Pr + wi * Qr + wr * Qi;                              \
        v2f Xi = Pi + wi * Qi - wr * Qr;                              \
        v2f s2 = __builtin_elementwise_fma(Xr, Xr, Xi * Xi);          \
        MG.x = sqrtf(s2.x); MG.y = sqrtf(s2.y);                       \
    }
    UNT(z0r, z0i, p0r, p0i, uc.x, us.x, mg0)
    UNT(z1r, z1i, p1r, p1i, uc.y, us.y, mg1)
    UNT(z2r, z2i, p2r, p2i, uc.z, us.z, mg2)
    UNT(z3r, z3i, p3r, p3i, uc.w, us.w, mg3)
#undef UNT

    // ---- store magnitudes interleaved: two b128 stores ----
    float* mw = magI[w];
    {
        float4 s0 = make_float4(mg0.x, mg0.y, mg1.x, mg1.y);
        float4 s1 = make_float4(mg2.x, mg2.y, mg3.x, mg3.y);
        *(float4*)(mw + 8 * mrev)     = s0;
        *(float4*)(mw + 8 * mrev + 4) = s1;
    }
    if (l < 4) {   // zero tail bins 256..263 (overread region, weights are 0)
        *(float4*)(mw + 512 + 4 * l) = make_float4(0.f, 0.f, 0.f, 0.f);
    }
    __builtin_amdgcn_wave_barrier();

    // ---- mel: lane l = filter l; 36 b64 reads, packed FMA ----
    v2f mel = splat(0.f);
    {
        const float* mbase = mw + sm2;
        #pragma unroll
        for (int jc = 0; jc < 9; jc++) {
            float4 fw = *(const float4*)(ws + WS_FBW + (jc * 64 + l) * 4);
            v2f ma = *(const v2f*)(mbase + 8 * jc + 0);
            v2f mb = *(const v2f*)(mbase + 8 * jc + 2);
            v2f mc = *(const v2f*)(mbase + 8 * jc + 4);
            v2f md = *(const v2f*)(mbase + 8 * jc + 6);
            mel = __builtin_elementwise_fma(splat(fw.x), ma, mel);
            mel = __builtin_elementwise_fma(splat(fw.y), mb, mel);
            mel = __builtin_elementwise_fma(splat(fw.z), mc, mel);
            mel = __builtin_elementwise_fma(splat(fw.w), md, mel);
        }
    }

    // ---- log, stage interleaved lm (one b64 write) ----
    float* lmi = lmI[w];
    if (l < NMELS) {
        v2f lg;
        lg.x = logf(mel.x + 1e-20f);
        lg.y = logf(mel.y + 1e-20f);
        *(v2f*)(lmi + 2 * l) = lg;
    }
    __builtin_amdgcn_wave_barrier();

    // ---- fused DCT+deltas matvec: b128 broadcast reads give packed pairs ----
    v2f acc = splat(0.f);
    int ii = (l < 39) ? l : 0;
    const float* mrow = ws + WS_MTT + ii * 40;
    #pragma unroll
    for (int g = 0; g < 10; g++) {
        float4 m4 = *(const float4*)(mrow + 4 * g);
        float4 q0 = *(const float4*)(lmi + 8 * g);
        float4 q1 = *(const float4*)(lmi + 8 * g + 4);
        v2f p0; p0.x = q0.x; p0.y = q0.y;
        v2f p1; p1.x = q0.z; p1.y = q0.w;
        v2f p2; p2.x = q1.x; p2.y = q1.y;
        v2f p3; p3.x = q1.z; p3.y = q1.w;
        acc = __builtin_elementwise_fma(splat(m4.x), p0, acc);
        acc = __builtin_elementwise_fma(splat(m4.y), p1, acc);
        acc = __builtin_elementwise_fma(splat(m4.z), p2, acc);
        acc = __builtin_elementwise_fma(splat(m4.w), p3, acc);
    }
    if (l < 39) {
        out[(size_t)fid0 * 39 + l] = acc.x;
        out[(size_t)fid1 * 39 + l] = acc.y;
    }
}

// ---------------------------------------------------------------------------
extern "C" void kernel_launch(void* const* d_in, const int* in_sizes, int n_in,
                              void* d_out, int out_size, void* d_ws, size_t ws_size,
                              hipStream_t stream) {
    const float* x = (const float*)d_in[0];
    float* ws = (float*)d_ws;
    float* out = (float*)d_out;

    init_tables<<<64, 256, 0, stream>>>(ws);
    mfcc_kernel<<<(BB * NF) / 8, NTHREADS, 0, stream>>>(x, ws, out);
}